// Round 1
// baseline (699.811 us; speedup 1.0000x reference)
//
#include <hip/hip_runtime.h>
#include <cstdint>
#include <cstddef>

// Problem constants (fixed by the reference)
#define S_TOK   8192
#define DMODEL  2048
#define NEXP    64
#define CAP     128
#define COMBINE_ELEMS 67108864ULL  // 8192*64*128

// jax.random.uniform(key(42)) reproduction.
// JAX >= 0.5 defaults jax_threefry_partitionable=True:
//   bits[idx] = o0 ^ o1 where (o0,o1) = threefry2x32((0,42), (idx>>32, idx&0xffffffff))
// Legacy (partitionable=False): counts split in halves, pair (idx, idx+N/2).
#define JAX_PARTITIONABLE 1

__device__ __forceinline__ unsigned rotl32(unsigned x, unsigned r) {
    return (x << r) | (x >> (32u - r));
}

__device__ __forceinline__ void threefry2x32(unsigned k0, unsigned k1,
                                             unsigned c0, unsigned c1,
                                             unsigned& o0, unsigned& o1) {
    unsigned ks[3] = {k0, k1, k0 ^ k1 ^ 0x1BD11BDAu};
    unsigned x0 = c0 + ks[0];
    unsigned x1 = c1 + ks[1];
    const unsigned rotA[4] = {13u, 15u, 26u, 6u};
    const unsigned rotB[4] = {17u, 29u, 16u, 24u};
#pragma unroll
    for (int i = 0; i < 5; ++i) {
        const unsigned* rr = (i & 1) ? rotB : rotA;
#pragma unroll
        for (int j = 0; j < 4; ++j) {
            x0 += x1;
            x1 = rotl32(x1, rr[j]);
            x1 ^= x0;
        }
        x0 += ks[(i + 1) % 3];
        x1 += ks[(i + 2) % 3] + (unsigned)(i + 1);
    }
    o0 = x0; o1 = x1;
}

__device__ __forceinline__ float jax_uniform_noise(unsigned idx) {
    unsigned bits;
#if JAX_PARTITIONABLE
    unsigned o0, o1;
    threefry2x32(0u, 42u, 0u /*idx>>32*/, idx, o0, o1);
    bits = o0 ^ o1;
#else
    const unsigned H = (S_TOK * NEXP) >> 1;  // 262144
    unsigned o0, o1;
    if (idx < H) { threefry2x32(0u, 42u, idx, idx + H, o0, o1); bits = o0; }
    else         { threefry2x32(0u, 42u, idx - H, idx, o0, o1); bits = o1; }
#endif
    unsigned fb = (bits >> 9) | 0x3f800000u;
    float f;
    __builtin_memcpy(&f, &fb, 4);
    return f - 1.0f;
}

// ---------------- Kernel 1: logits = x @ wg^T  ([8192,64]) ----------------
// 256 blocks, 256 thr. Tile: 32 tokens x 64 experts, BK=64.
// Thread computes 2 tokens x 4 experts (experts strided by 16 for LDS banking).
__global__ __launch_bounds__(256) void gemm_logits(const float* __restrict__ x,
                                                   const float* __restrict__ wg,
                                                   float* __restrict__ logits) {
    __shared__ __align__(16) float xs[32][68];   // +4 pad keeps b128 rows rotating banks
    __shared__ __align__(16) float wsh[64][68];
    const int tid = threadIdx.x;
    const int s0 = blockIdx.x * 32;
    const int g  = tid & 15;          // expert group: handles g, g+16, g+32, g+48
    const int tt = (tid >> 4) * 2;    // token pair
    float acc[2][4] = {{0.f, 0.f, 0.f, 0.f}, {0.f, 0.f, 0.f, 0.f}};

    for (int k0 = 0; k0 < DMODEL; k0 += 64) {
#pragma unroll
        for (int i = 0; i < 2; ++i) {  // x chunk: 32x64 = 512 float4
            int slot = tid + i * 256;
            int r = slot >> 4, c4 = (slot & 15) * 4;
            float4 v = *(const float4*)&x[(size_t)(s0 + r) * DMODEL + k0 + c4];
            *(float4*)&xs[r][c4] = v;
        }
#pragma unroll
        for (int i = 0; i < 4; ++i) {  // wg chunk: 64x64 = 1024 float4
            int slot = tid + i * 256;
            int r = slot >> 4, c4 = (slot & 15) * 4;
            float4 v = *(const float4*)&wg[(size_t)r * DMODEL + k0 + c4];
            *(float4*)&wsh[r][c4] = v;
        }
        __syncthreads();
#pragma unroll
        for (int k4 = 0; k4 < 64; k4 += 4) {
            float4 xv0 = *(float4*)&xs[tt][k4];
            float4 xv1 = *(float4*)&xs[tt + 1][k4];
#pragma unroll
            for (int j = 0; j < 4; ++j) {
                float4 w = *(float4*)&wsh[g + 16 * j][k4];
                // strict k-ascending accumulation order (deterministic, fma-contracted)
                acc[0][j] += xv0.x * w.x; acc[0][j] += xv0.y * w.y;
                acc[0][j] += xv0.z * w.z; acc[0][j] += xv0.w * w.w;
                acc[1][j] += xv1.x * w.x; acc[1][j] += xv1.y * w.y;
                acc[1][j] += xv1.z * w.z; acc[1][j] += xv1.w * w.w;
            }
        }
        __syncthreads();
    }
#pragma unroll
    for (int i = 0; i < 2; ++i)
#pragma unroll
        for (int j = 0; j < 4; ++j)
            logits[(size_t)(s0 + tt + i) * NEXP + g + 16 * j] = acc[i][j];
}

// ------------- Kernel 2: softmax + argmax + me/cnt + noise -------------
// One wave (64 lanes) per token; lane == expert.
__global__ __launch_bounds__(256) void softmax_argmax(const float* __restrict__ logits,
                                                      int* __restrict__ tok_expert,
                                                      float* __restrict__ tok_gate,
                                                      float* __restrict__ tok_noise,
                                                      float* __restrict__ me_sum,
                                                      int* __restrict__ cnt) {
    const int tid = threadIdx.x;
    const int lane = tid & 63;
    const int w = tid >> 6;
    const int s = blockIdx.x * 4 + w;

    float v = logits[(size_t)s * NEXP + lane];
    float m = v;
#pragma unroll
    for (int off = 32; off; off >>= 1) m = fmaxf(m, __shfl_xor(m, off));
    float ev = expf(v - m);
    float sum = ev;
#pragma unroll
    for (int off = 32; off; off >>= 1) sum += __shfl_xor(sum, off);
    float gate = ev / sum;

    // argmax over normalized gates, ties -> lowest index (jnp.argmax semantics)
    float bv = gate; int bi = lane;
#pragma unroll
    for (int off = 32; off; off >>= 1) {
        float ov = __shfl_xor(bv, off);
        int   oi = __shfl_xor(bi, off);
        if (ov > bv || (ov == bv && oi < bi)) { bv = ov; bi = oi; }
    }
    if (lane == 0) {
        tok_expert[s] = bi;
        tok_gate[s]   = bv;
        tok_noise[s]  = jax_uniform_noise((unsigned)(s * NEXP + bi));
        atomicAdd(&cnt[bi], 1);
    }

    __shared__ float mep[256];
    mep[tid] = gate;
    __syncthreads();
    if (tid < 64) {
        float t = mep[tid] + mep[tid + 64] + mep[tid + 128] + mep[tid + 192];
        atomicAdd(&me_sum[tid], t);
    }
}

// ------------- Kernel 3: l_aux + exp_counts -------------
__global__ void finalize(const float* __restrict__ me_sum, const int* __restrict__ cnt,
                         float* __restrict__ d_out) {
    const int e = threadIdx.x;  // 64 threads
    float me = me_sum[e] / (float)S_TOK;
    float ce = (float)cnt[e] / (float)S_TOK;
    float p = me * ce;
#pragma unroll
    for (int off = 32; off; off >>= 1) p += __shfl_xor(p, off);
    if (e == 0) d_out[0] = p * (float)NEXP;
    d_out[1 + 2 * COMBINE_ELEMS + e] = (float)cnt[e];  // exp_counts (pre-capacity)
}

// ------------- Kernel 4: per-expert top-capacity selection + scatter -------------
#define MAXN 2048
__global__ __launch_bounds__(256) void select_scatter(const int* __restrict__ tok_expert,
                                                      const float* __restrict__ tok_gate,
                                                      const float* __restrict__ tok_noise,
                                                      float* __restrict__ d_out) {
    const int e = blockIdx.x;
    __shared__ int   toks[MAXN];
    __shared__ float noi[MAXN];
    __shared__ int   rnk[MAXN];
    __shared__ int   n_sh;
    if (threadIdx.x == 0) n_sh = 0;
    __syncthreads();

    for (int s = threadIdx.x; s < S_TOK; s += 256) {
        if (tok_expert[s] == e) {
            int i = atomicAdd(&n_sh, 1);
            if (i < MAXN) { toks[i] = s; noi[i] = tok_noise[s]; }
        }
    }
    __syncthreads();
    int n = n_sh; if (n > MAXN) n = MAXN;

    // rank by noise desc, ties -> lower token index first (lax.top_k stability)
    for (int i = threadIdx.x; i < n; i += 256) {
        float vi = noi[i]; int si = toks[i];
        int r = 0;
        for (int j = 0; j < n; ++j) {
            float vj = noi[j];
            r += (vj > vi) || (vj == vi && toks[j] < si);
        }
        rnk[i] = r;
    }
    __syncthreads();

    for (int i = threadIdx.x; i < n; i += 256) {
        if (rnk[i] < CAP) {
            int si = toks[i];
            int loc = 0;  // cumsum position among kept tokens, by token index
            for (int j = 0; j < n; ++j)
                loc += (rnk[j] < CAP) && (toks[j] < si);
            size_t base = 1ULL + (((size_t)si * NEXP + e) * CAP + (size_t)loc);
            d_out[base] = tok_gate[si];                 // combine_weights
            d_out[base + COMBINE_ELEMS] = 1.0f;        // dispatch_mask (gate>0 always)
        }
    }
}

extern "C" void kernel_launch(void* const* d_in, const int* in_sizes, int n_in,
                              void* d_out, int out_size, void* d_ws, size_t ws_size,
                              hipStream_t stream) {
    const float* x  = (const float*)d_in[0];
    const float* wg = (const float*)d_in[1];
    float* out = (float*)d_out;
    float* ws  = (float*)d_ws;

    // ws layout (float offsets)
    float* logits     = ws;                         // 524288
    int*   tok_expert = (int*)(ws + 524288);        // 8192
    float* tok_gate   = ws + 524288 + 8192;         // 8192
    float* tok_noise  = ws + 524288 + 16384;        // 8192
    float* me_sum     = ws + 524288 + 24576;        // 64
    int*   cnt        = (int*)(ws + 524288 + 24640);// 64
    // total ~2.2 MB of ws

    // out is poisoned each launch; combine/dispatch are sparse -> zero everything.
    hipMemsetAsync(d_out, 0, (size_t)out_size * sizeof(float), stream);
    hipMemsetAsync(me_sum, 0, 128 * sizeof(float), stream);

    gemm_logits<<<S_TOK / 32, 256, 0, stream>>>(x, wg, logits);
    softmax_argmax<<<S_TOK / 4, 256, 0, stream>>>(logits, tok_expert, tok_gate,
                                                  tok_noise, me_sum, cnt);
    finalize<<<1, 64, 0, stream>>>(me_sum, cnt, out);
    select_scatter<<<NEXP, 256, 0, stream>>>(tok_expert, tok_gate, tok_noise, out);
}

// Round 3
// 653.673 us; speedup vs baseline: 1.0706x; 1.0706x over previous
//
#include <hip/hip_runtime.h>
#include <cstdint>
#include <cstddef>

// Problem constants (fixed by the reference)
#define S_TOK   8192
#define DMODEL  2048
#define NEXP    64
#define CAP     128
#define COMBINE_ELEMS 67108864ULL            // 8192*64*128
#define OUT_ELEMS     134217793ULL           // 1 + 2*COMBINE + 64
#define OUT_F4        33554448ULL            // floor(OUT_ELEMS/4); tail elem 134217792

typedef float floatx4 __attribute__((ext_vector_type(4)));  // nontemporal-compatible

// jax.random.uniform(key(42)): JAX >= 0.5 threefry_partitionable path:
// bits[idx] = o0 ^ o1 of threefry2x32((0,42), (0, idx))
__device__ __forceinline__ unsigned rotl32(unsigned x, unsigned r) {
    return (x << r) | (x >> (32u - r));
}

__device__ __forceinline__ void threefry2x32(unsigned k0, unsigned k1,
                                             unsigned c0, unsigned c1,
                                             unsigned& o0, unsigned& o1) {
    unsigned ks[3] = {k0, k1, k0 ^ k1 ^ 0x1BD11BDAu};
    unsigned x0 = c0 + ks[0];
    unsigned x1 = c1 + ks[1];
    const unsigned rotA[4] = {13u, 15u, 26u, 6u};
    const unsigned rotB[4] = {17u, 29u, 16u, 24u};
#pragma unroll
    for (int i = 0; i < 5; ++i) {
        const unsigned* rr = (i & 1) ? rotB : rotA;
#pragma unroll
        for (int j = 0; j < 4; ++j) {
            x0 += x1;
            x1 = rotl32(x1, rr[j]);
            x1 ^= x0;
        }
        x0 += ks[(i + 1) % 3];
        x1 += ks[(i + 2) % 3] + (unsigned)(i + 1);
    }
    o0 = x0; o1 = x1;
}

__device__ __forceinline__ float jax_uniform_noise(unsigned idx) {
    unsigned o0, o1;
    threefry2x32(0u, 42u, 0u, idx, o0, o1);
    unsigned bits = o0 ^ o1;
    unsigned fb = (bits >> 9) | 0x3f800000u;
    float f;
    __builtin_memcpy(&f, &fb, 4);
    return f - 1.0f;
}

// ---------------- Kernel 1: fused logits GEMM + d_out zero-fill ----------------
// blockIdx < 256  : GEMM block, tile 32 tokens x 64 experts, BK=64, 128 threads,
//                   thread = 4 tokens x 4 experts (8 b128 LDS reads per 64 FMAs).
// blockIdx >= 256 : zero-fill blocks, grid-stride float4 nontemporal stores over
//                   d_out (537 MB). These overlap the LDS/VALU-bound GEMM blocks
//                   on other wave slots -> total ~= max(write-BW floor, gemm).
#define GEMM_BLOCKS 256
#define ZERO_BLOCKS 4096
__global__ __launch_bounds__(128) void gemm_zero(const float* __restrict__ x,
                                                 const float* __restrict__ wg,
                                                 float* __restrict__ logits,
                                                 float* __restrict__ d_out) {
    if (blockIdx.x >= GEMM_BLOCKS) {
        const size_t zb = blockIdx.x - GEMM_BLOCKS;
        floatx4* o4 = (floatx4*)d_out;
        const floatx4 z = {0.f, 0.f, 0.f, 0.f};
        const size_t stride = (size_t)ZERO_BLOCKS * 128;
        for (size_t i = zb * 128 + threadIdx.x; i < OUT_F4; i += stride)
            __builtin_nontemporal_store(z, &o4[i]);
        if (zb == 0 && threadIdx.x == 0) d_out[OUT_ELEMS - 1] = 0.f;
        return;
    }

    __shared__ __align__(16) float xs[32][68];
    __shared__ __align__(16) float wsh[64][68];
    const int tid = threadIdx.x;
    const int s0 = blockIdx.x * 32;
    const int g  = tid & 15;          // experts g, g+16, g+32, g+48
    const int ty = tid >> 4;          // tokens ty*4 .. ty*4+3
    float acc[4][4];
#pragma unroll
    for (int i = 0; i < 4; ++i)
#pragma unroll
        for (int j = 0; j < 4; ++j) acc[i][j] = 0.f;

    for (int k0 = 0; k0 < DMODEL; k0 += 64) {
#pragma unroll
        for (int i = 0; i < 4; ++i) {  // x chunk: 32x64 = 512 float4, 128 thr
            int slot = tid + i * 128;
            int r = slot >> 4, c4 = (slot & 15) * 4;
            float4 v = *(const float4*)&x[(size_t)(s0 + r) * DMODEL + k0 + c4];
            *(float4*)&xs[r][c4] = v;
        }
#pragma unroll
        for (int i = 0; i < 8; ++i) {  // wg chunk: 64x64 = 1024 float4
            int slot = tid + i * 128;
            int r = slot >> 4, c4 = (slot & 15) * 4;
            float4 v = *(const float4*)&wg[(size_t)r * DMODEL + k0 + c4];
            *(float4*)&wsh[r][c4] = v;
        }
        __syncthreads();
#pragma unroll
        for (int k4 = 0; k4 < 64; k4 += 4) {
            float4 xv[4], wv[4];
#pragma unroll
            for (int t = 0; t < 4; ++t) xv[t] = *(float4*)&xs[ty * 4 + t][k4];
#pragma unroll
            for (int j = 0; j < 4; ++j) wv[j] = *(float4*)&wsh[g + 16 * j][k4];
#pragma unroll
            for (int t = 0; t < 4; ++t)
#pragma unroll
                for (int j = 0; j < 4; ++j) {
                    // k-ascending chain per output: bit-identical to round-1 kernel
                    acc[t][j] += xv[t].x * wv[j].x; acc[t][j] += xv[t].y * wv[j].y;
                    acc[t][j] += xv[t].z * wv[j].z; acc[t][j] += xv[t].w * wv[j].w;
                }
        }
        __syncthreads();
    }
#pragma unroll
    for (int t = 0; t < 4; ++t)
#pragma unroll
        for (int j = 0; j < 4; ++j)
            logits[(size_t)(s0 + ty * 4 + t) * NEXP + g + 16 * j] = acc[t][j];
}

// ------------- Kernel 2: softmax + argmax + me partials + noise -------------
// 256 blocks x 256 thr; block handles 32 tokens (each wave 8 sequential tokens).
// No global atomics: per-block me partial -> ws me_part[block*64+e].
__global__ __launch_bounds__(256) void softmax_stats(const float* __restrict__ logits,
                                                     int* __restrict__ tok_expert,
                                                     float* __restrict__ tok_gate,
                                                     float* __restrict__ tok_noise,
                                                     float* __restrict__ me_part) {
    const int tid = threadIdx.x;
    const int lane = tid & 63;
    const int w = tid >> 6;
    float me_acc = 0.f;

#pragma unroll
    for (int it = 0; it < 8; ++it) {
        const int s = blockIdx.x * 32 + w * 8 + it;
        float v = logits[(size_t)s * NEXP + lane];
        float m = v;
#pragma unroll
        for (int off = 32; off; off >>= 1) m = fmaxf(m, __shfl_xor(m, off));
        float ev = expf(v - m);
        float sum = ev;
#pragma unroll
        for (int off = 32; off; off >>= 1) sum += __shfl_xor(sum, off);
        float gate = ev / sum;
        me_acc += gate;

        float bv = gate; int bi = lane;
#pragma unroll
        for (int off = 32; off; off >>= 1) {
            float ov = __shfl_xor(bv, off);
            int   oi = __shfl_xor(bi, off);
            if (ov > bv || (ov == bv && oi < bi)) { bv = ov; bi = oi; }
        }
        if (lane == 0) {
            tok_expert[s] = bi;
            tok_gate[s]   = bv;
            tok_noise[s]  = jax_uniform_noise((unsigned)(s * NEXP + bi));
        }
    }

    __shared__ float mep[4][64];
    mep[w][lane] = me_acc;
    __syncthreads();
    if (tid < 64)
        me_part[(size_t)blockIdx.x * 64 + tid] =
            mep[0][tid] + mep[1][tid] + mep[2][tid] + mep[3][tid];
}

// ------------- Kernel 3: per-expert top-capacity selection + scatter + count ----
#define MAXN 2048
__global__ __launch_bounds__(256) void select_scatter(const int* __restrict__ tok_expert,
                                                      const float* __restrict__ tok_gate,
                                                      const float* __restrict__ tok_noise,
                                                      int* __restrict__ cnt,
                                                      float* __restrict__ d_out) {
    const int e = blockIdx.x;
    __shared__ int   toks[MAXN];
    __shared__ float noi[MAXN];
    __shared__ int   rnk[MAXN];
    __shared__ int   n_sh;
    if (threadIdx.x == 0) n_sh = 0;
    __syncthreads();

    for (int s = threadIdx.x; s < S_TOK; s += 256) {
        if (tok_expert[s] == e) {
            int i = atomicAdd(&n_sh, 1);
            if (i < MAXN) { toks[i] = s; noi[i] = tok_noise[s]; }
        }
    }
    __syncthreads();
    if (threadIdx.x == 0) cnt[e] = n_sh;   // exact pre-capacity count
    int n = n_sh; if (n > MAXN) n = MAXN;

    // rank by noise desc, ties -> lower token index (lax.top_k stability)
    for (int i = threadIdx.x; i < n; i += 256) {
        float vi = noi[i]; int si = toks[i];
        int r = 0;
        for (int j = 0; j < n; ++j) {
            float vj = noi[j];
            r += (vj > vi) || (vj == vi && toks[j] < si);
        }
        rnk[i] = r;
    }
    __syncthreads();

    for (int i = threadIdx.x; i < n; i += 256) {
        if (rnk[i] < CAP) {
            int si = toks[i];
            int loc = 0;  // cumsum slot among kept tokens, by token index
            for (int j = 0; j < n; ++j)
                loc += (rnk[j] < CAP) && (toks[j] < si);
            size_t base = 1ULL + (((size_t)si * NEXP + e) * CAP + (size_t)loc);
            d_out[base] = tok_gate[si];              // combine_weights
            d_out[base + COMBINE_ELEMS] = 1.0f;      // dispatch_mask
        }
    }
}

// ------------- Kernel 4: l_aux + exp_counts (after select_scatter) -------------
__global__ void finalize(const float* __restrict__ me_part, const int* __restrict__ cnt,
                         float* __restrict__ d_out) {
    const int e = threadIdx.x;  // 64 threads
    float me = 0.f;
    for (int b = 0; b < 256; ++b) me += me_part[(size_t)b * 64 + e];
    me /= (float)S_TOK;
    int c = cnt[e];
    float ce = (float)c / (float)S_TOK;
    float p = me * ce;
#pragma unroll
    for (int off = 32; off; off >>= 1) p += __shfl_xor(p, off);
    if (e == 0) d_out[0] = p * (float)NEXP;
    d_out[1 + 2 * COMBINE_ELEMS + e] = (float)c;
}

extern "C" void kernel_launch(void* const* d_in, const int* in_sizes, int n_in,
                              void* d_out, int out_size, void* d_ws, size_t ws_size,
                              hipStream_t stream) {
    const float* x  = (const float*)d_in[0];
    const float* wg = (const float*)d_in[1];
    float* out = (float*)d_out;
    float* ws  = (float*)d_ws;

    // ws layout (float offsets); everything fully written each launch, no memsets.
    float* logits     = ws;                          // 524288
    int*   tok_expert = (int*)(ws + 524288);         // 8192
    float* tok_gate   = ws + 532480;                 // 8192
    float* tok_noise  = ws + 540672;                 // 8192
    int*   cnt        = (int*)(ws + 548864);         // 64
    float* me_part    = ws + 548928;                 // 256*64

    gemm_zero<<<GEMM_BLOCKS + ZERO_BLOCKS, 128, 0, stream>>>(x, wg, logits, out);
    softmax_stats<<<S_TOK / 32, 256, 0, stream>>>(logits, tok_expert, tok_gate,
                                                  tok_noise, me_part);
    select_scatter<<<NEXP, 256, 0, stream>>>(tok_expert, tok_gate, tok_noise, cnt, out);
    finalize<<<1, 64, 0, stream>>>(me_part, cnt, out);
}